// Round 12
// baseline (393.616 us; speedup 1.0000x reference)
//
#include <hip/hip_runtime.h>
#include <stdint.h>

using bf16x8 = __attribute__((ext_vector_type(8))) short;
using f32x4  = __attribute__((ext_vector_type(4))) float;

__device__ __forceinline__ unsigned short f2bf(float f) {
  uint32_t x = __float_as_uint(f);
  x += 0x7fffu + ((x >> 16) & 1u);
  return (unsigned short)(x >> 16);
}
__device__ __forceinline__ float bf2f(unsigned short u) {
  return __uint_as_float(((uint32_t)u) << 16);
}
__device__ __forceinline__ uint32_t cvtpk2(float lo, float hi) {
  uint32_t r;
  asm("v_cvt_pk_bf16_f32 %0, %1, %2" : "=v"(r) : "v"(lo), "v"(hi));
  return r;
}
__device__ __forceinline__ float silu_f(float v) {
  float e = __expf(-v);
  return v * __builtin_amdgcn_rcpf(1.0f + e);
}
__device__ __forceinline__ void unpack2(uint32_t u, float& lo, float& hi) {
  lo = __uint_as_float(u << 16);
  hi = __uint_as_float(u & 0xffff0000u);
}

// Ms rotated-swizzle addressing: row stride 136 ushort (272B, b128-aligned).
__device__ __forceinline__ int msoff(int row, int col) {
  return row * 136 + ((((col >> 3) + row * 4) & 15) << 3) + (col & 7);
}
__device__ __forceinline__ int msoff_slot(int row, int slot) {
  return row * 136 + (((slot + row * 4) & 15) << 3);
}

// ---- prep: weights -> bf16, W1p split layout, w1c column, flag sniff ----
__global__ void prep_kernel(const float* __restrict__ We1, const float* __restrict__ We2,
                            const float* __restrict__ Wn1, const float* __restrict__ Wn2,
                            const float* __restrict__ Wc1, const int* __restrict__ ei,
                            unsigned short* __restrict__ W1p, unsigned short* __restrict__ W2b,
                            unsigned short* __restrict__ N1b, unsigned short* __restrict__ N2b,
                            unsigned short* __restrict__ W3b, float* __restrict__ w1c,
                            int* __restrict__ flag) {
  int i = blockIdx.x * 256 + threadIdx.x;      // 0..32767
  if (i < 256 * 128) {
    // W1p[c][k]: c<128 -> Ws row c (We1[c][0:128]); c>=128 -> Wd row c-128 (We1[c-128][128:256])
    int c = i >> 7, k = i & 127;
    W1p[i] = f2bf(We1[(size_t)(c & 127) * 257 + ((c >> 7) << 7) + k]);
    N1b[i] = f2bf(Wn1[i]);
  }
  if (i < 128 * 128) {
    W2b[i] = f2bf(We2[i]);
    W3b[i] = f2bf(Wc1[i]);
    N2b[i] = f2bf(Wn2[i]);
  }
  if (i < 128) w1c[i] = We1[i * 257 + 256];
  if (i == 0) {
    int allz = 1;
    for (int k = 0; k < 64; ++k) allz &= (ei[2 * k + 1] == 0);
    *flag = allz;   // 1 => int64 indices
  }
}

// ---- CSR-order build: hist + 3-kernel parallel scan + scatter ----
__global__ void hist_kernel(const int* __restrict__ ei, const int* __restrict__ flag,
                            int* __restrict__ deg, int E) {
  int e = blockIdx.x * 256 + threadIdx.x;
  if (e >= E) return;
  int d = (*flag) ? (int)((const long long*)ei)[(size_t)E + e] : ei[E + e];
  atomicAdd(&deg[d], 1);
}

__global__ void scanA_kernel(const int* __restrict__ deg, int* __restrict__ offs,
                             int* __restrict__ bsum, int N) {
  __shared__ int sh[256];
  int t = threadIdx.x, idx = blockIdx.x * 256 + t;
  int v = (idx < N) ? deg[idx] : 0;
  sh[t] = v;
  __syncthreads();
#pragma unroll
  for (int d = 1; d < 256; d <<= 1) {
    int u = (t >= d) ? sh[t - d] : 0;
    __syncthreads();
    sh[t] += u;
    __syncthreads();
  }
  if (idx < N) offs[idx] = sh[t] - v;
  if (t == 255) bsum[blockIdx.x] = sh[255];
}

__global__ void scanB_kernel(int* __restrict__ bsum, int* __restrict__ offs,
                             int nb, int N) {
  __shared__ int sh[256];
  int t = threadIdx.x;
  int v = (t < nb) ? bsum[t] : 0;
  sh[t] = v;
  __syncthreads();
#pragma unroll
  for (int d = 1; d < 256; d <<= 1) {
    int u = (t >= d) ? sh[t - d] : 0;
    __syncthreads();
    sh[t] += u;
    __syncthreads();
  }
  bsum[t] = sh[t] - v;
  if (t == 255) offs[N] = sh[255];
}

__global__ void scanC_kernel(const int* __restrict__ bsum, int* __restrict__ offs,
                             int* __restrict__ cursor, int N) {
  int idx = blockIdx.x * 256 + threadIdx.x;
  if (idx < N) {
    int o = offs[idx] + bsum[blockIdx.x];
    offs[idx] = o;
    cursor[idx] = o;
  }
}

// scatter: dst-sorted packed (src,dst) pairs
__global__ void scatter_kernel(const int* __restrict__ ei, const int* __restrict__ flag,
                               int* __restrict__ cursor, int2* __restrict__ sd_s, int E) {
  int e = blockIdx.x * 256 + threadIdx.x;
  if (e >= E) return;
  int s, d;
  if (*flag) {
    s = (int)((const long long*)ei)[e];
    d = (int)((const long long*)ei)[(size_t)E + e];
  } else {
    s = ei[e];
    d = ei[E + e];
  }
  int pos = atomicAdd(&cursor[d], 1);
  int2 p; p.x = s; p.y = d;
  sd_s[pos] = p;
}

// ---- proj: Ps[n] = h[n]@Ws^T + be1 ; Pd[n] = h[n]@Wd^T  (bf16, split arrays) ----
__global__ __launch_bounds__(256) void proj_kernel(
    const float* __restrict__ h, const float* __restrict__ be1,
    const unsigned short* __restrict__ W1p,
    unsigned short* __restrict__ Ps, unsigned short* __restrict__ Pd, int N) {
  const int tid = threadIdx.x;
  const int base = blockIdx.x * 64;
  const int w = tid >> 6, lane = tid & 63, lg = lane >> 4, lr = lane & 15;

  f32x4 acc[4][4];
#pragma unroll
  for (int m = 0; m < 4; ++m)
#pragma unroll
    for (int n = 0; n < 4; ++n) { f32x4 z = {0.f,0.f,0.f,0.f}; acc[m][n] = z; }

#pragma unroll
  for (int k0 = 0; k0 < 4; ++k0) {
    bf16x8 b[4];
#pragma unroll
    for (int n = 0; n < 4; ++n)
      b[n] = *(const bf16x8*)(W1p + ((w * 64 + n * 16 + lr) << 7) + k0 * 32 + lg * 8);
#pragma unroll
    for (int m = 0; m < 4; ++m) {
      int row = base + m * 16 + lr; if (row >= N) row = N - 1;
      const float* p = h + (size_t)row * 128 + k0 * 32 + lg * 8;
      float4 fa = *(const float4*)p;
      float4 fb = *(const float4*)(p + 4);
      uint32_t u0 = cvtpk2(fa.x, fa.y), u1 = cvtpk2(fa.z, fa.w);
      uint32_t u2 = cvtpk2(fb.x, fb.y), u3 = cvtpk2(fb.z, fb.w);
      union { uint32_t u[4]; bf16x8 v; } cv;
      cv.u[0] = u0; cv.u[1] = u1; cv.u[2] = u2; cv.u[3] = u3;
#pragma unroll
      for (int n = 0; n < 4; ++n)
        acc[m][n] = __builtin_amdgcn_mfma_f32_16x16x32_bf16(cv.v, b[n], acc[m][n], 0, 0, 0);
    }
  }
#pragma unroll
  for (int n = 0; n < 4; ++n) {
    int o = w * 64 + n * 16 + lr;
    unsigned short* dstp = (o < 128) ? Ps : Pd;
    int oo = o & 127;
    float add = (o < 128) ? be1[o] : 0.f;    // fold be1 into Ps half
#pragma unroll
    for (int m = 0; m < 4; ++m)
#pragma unroll
      for (int r = 0; r < 4; ++r) {
        int row = base + m * 16 + lg * 4 + r;
        if (row < N) dstp[(size_t)row * 128 + oo] = f2bf(acc[m][n][r] + add);
      }
  }
}

// ---- fused edge kernel: 64 dst-sorted edges/block, XCD-swizzled block order;
//      gather Ps/Pd + combine, GEMM2, GEMM3, 4-way segmented aggregation ----
__global__ __launch_bounds__(256, 6) void edge_kernel(
    const unsigned short* __restrict__ Ps, const unsigned short* __restrict__ Pd,
    const float* __restrict__ x, const int2* __restrict__ sd_s,
    const float* __restrict__ w1c,
    const float* __restrict__ be2, const float* __restrict__ bc1,
    const float* __restrict__ Wc2,
    const unsigned short* __restrict__ W2b, const unsigned short* __restrict__ W3b,
    float* __restrict__ aggH, float* __restrict__ coordX, int E) {
  __shared__ __align__(16) unsigned short Ms[64 * 136];  // combine out, then Ms2
  __shared__ float swred[4][64];
  __shared__ int   ssrc[64], sdst[64];
  __shared__ float sds[64];
  __shared__ float sdif[64][3];

  const int tid   = threadIdx.x;
  // XCD-aware bijective swizzle (m204): consecutive dst-ranges -> same XCD's L2
  const int nwg = gridDim.x;
  const int q = nwg >> 3, r = nwg & 7;
  const int xcd = blockIdx.x & 7, pos = blockIdx.x >> 3;
  const int logical = (xcd < r ? xcd * (q + 1) : r * (q + 1) + (xcd - r) * q) + pos;
  const int tbase = logical * 64;
  const int w = tid >> 6, lane = tid & 63, lg = lane >> 4, lr = lane & 15;

  // phase 0: indices + geometry (dst-sorted, coalesced int2 loads)
  if (tid < 64) {
    int p0 = tbase + tid;
    int s = 0, d = 0;
    if (p0 < E) { int2 p = sd_s[p0]; s = p.x; d = p.y; }
    ssrc[tid] = s; sdst[tid] = d;
    float dx = x[s * 3 + 0] - x[d * 3 + 0];
    float dy = x[s * 3 + 1] - x[d * 3 + 1];
    float dz = x[s * 3 + 2] - x[d * 3 + 2];
    sdif[tid][0] = dx; sdif[tid][1] = dy; sdif[tid][2] = dz;
    sds[tid] = dx * dx + dy * dy + dz * dz;
  }
  __syncthreads();

  // ---- gather Ps[src]/Pd[dst], combine + silu -> Ms (2x2 chunks: low live-reg) ----
  {
    const float4* w4 = (const float4*)w1c;
#pragma unroll
    for (int ch = 0; ch < 2; ++ch) {
      uint4 av[2], bv[2];
#pragma unroll
      for (int it = 0; it < 2; ++it) {
        int idx = tid + (ch * 2 + it) * 256;   // 0..1023
        int e = idx >> 4, seg = idx & 15;
        av[it] = *(const uint4*)(Ps + (size_t)ssrc[e] * 128 + seg * 8);
        bv[it] = *(const uint4*)(Pd + (size_t)sdst[e] * 128 + seg * 8);
      }
#pragma unroll
      for (int it = 0; it < 2; ++it) {
        int idx = tid + (ch * 2 + it) * 256;
        int e = idx >> 4, seg = idx & 15;
        float dsv = sds[e];
        float4 wA = w4[seg * 2], wB = w4[seg * 2 + 1];
        float a0,a1,a2,a3,a4,a5,a6,a7, b0,b1,b2,b3,b4,b5,b6,b7;
        unpack2(((uint32_t*)&av[it])[0], a0, a1);
        unpack2(((uint32_t*)&av[it])[1], a2, a3);
        unpack2(((uint32_t*)&av[it])[2], a4, a5);
        unpack2(((uint32_t*)&av[it])[3], a6, a7);
        unpack2(((uint32_t*)&bv[it])[0], b0, b1);
        unpack2(((uint32_t*)&bv[it])[1], b2, b3);
        unpack2(((uint32_t*)&bv[it])[2], b4, b5);
        unpack2(((uint32_t*)&bv[it])[3], b6, b7);
        float v0 = silu_f(a0 + b0 + dsv * wA.x);
        float v1 = silu_f(a1 + b1 + dsv * wA.y);
        float v2 = silu_f(a2 + b2 + dsv * wA.z);
        float v3 = silu_f(a3 + b3 + dsv * wA.w);
        float v4 = silu_f(a4 + b4 + dsv * wB.x);
        float v5 = silu_f(a5 + b5 + dsv * wB.y);
        float v6 = silu_f(a6 + b6 + dsv * wB.z);
        float v7 = silu_f(a7 + b7 + dsv * wB.w);
        uint4 o;
        o.x = cvtpk2(v0, v1); o.y = cvtpk2(v2, v3);
        o.z = cvtpk2(v4, v5); o.w = cvtpk2(v6, v7);
        *(uint4*)(&Ms[msoff_slot(e, seg)]) = o;
      }
    }
  }
  __syncthreads();

  // ---- GEMM2: Ms @ We2^T (+be2), silu -> Ms2 (same arena) ----
  {
    f32x4 acc[4][2];
#pragma unroll
    for (int m = 0; m < 4; ++m) { f32x4 z = {0.f,0.f,0.f,0.f}; acc[m][0] = z; acc[m][1] = z; }
#pragma unroll
    for (int k0 = 0; k0 < 4; ++k0) {
      bf16x8 b0 = *(const bf16x8*)(W2b + ((w * 32 + lr)      << 7) + k0 * 32 + lg * 8);
      bf16x8 b1 = *(const bf16x8*)(W2b + ((w * 32 + 16 + lr) << 7) + k0 * 32 + lg * 8);
#pragma unroll
      for (int m = 0; m < 4; ++m) {
        int row = m * 16 + lr;
        bf16x8 a = *(const bf16x8*)(&Ms[msoff_slot(row, k0 * 4 + lg)]);
        acc[m][0] = __builtin_amdgcn_mfma_f32_16x16x32_bf16(a, b0, acc[m][0], 0, 0, 0);
        acc[m][1] = __builtin_amdgcn_mfma_f32_16x16x32_bf16(a, b1, acc[m][1], 0, 0, 0);
      }
    }
    uint32_t pk[4][2][2];
#pragma unroll
    for (int n = 0; n < 2; ++n) {
      int o = w * 32 + n * 16 + lr;
      float b2v = be2[o];
#pragma unroll
      for (int m = 0; m < 4; ++m)
#pragma unroll
        for (int r2 = 0; r2 < 4; r2 += 2)
          pk[m][n][r2 >> 1] = cvtpk2(silu_f(acc[m][n][r2] + b2v),
                                     silu_f(acc[m][n][r2 + 1] + b2v));
    }
    __syncthreads();   // all waves done READING Ms
#pragma unroll
    for (int n = 0; n < 2; ++n) {
      int o = w * 32 + n * 16 + lr;
#pragma unroll
      for (int m = 0; m < 4; ++m)
#pragma unroll
        for (int r2 = 0; r2 < 4; r2 += 2) {
          int row = m * 16 + lg * 4 + r2;
          uint32_t u = pk[m][n][r2 >> 1];
          Ms[msoff(row, o)]     = (unsigned short)(u & 0xffffu);
          Ms[msoff(row + 1, o)] = (unsigned short)(u >> 16);
        }
    }
  }
  __syncthreads();

  // ---- GEMM3: Ms2 @ Wc1^T, silu, dot Wc2 -> swred ----
  {
    f32x4 acc[4][2];
#pragma unroll
    for (int m = 0; m < 4; ++m) { f32x4 z = {0.f,0.f,0.f,0.f}; acc[m][0] = z; acc[m][1] = z; }
#pragma unroll
    for (int k0 = 0; k0 < 4; ++k0) {
      bf16x8 b0 = *(const bf16x8*)(W3b + ((w * 32 + lr)      << 7) + k0 * 32 + lg * 8);
      bf16x8 b1 = *(const bf16x8*)(W3b + ((w * 32 + 16 + lr) << 7) + k0 * 32 + lg * 8);
#pragma unroll
      for (int m = 0; m < 4; ++m) {
        int row = m * 16 + lr;
        bf16x8 a = *(const bf16x8*)(&Ms[msoff_slot(row, k0 * 4 + lg)]);
        acc[m][0] = __builtin_amdgcn_mfma_f32_16x16x32_bf16(a, b0, acc[m][0], 0, 0, 0);
        acc[m][1] = __builtin_amdgcn_mfma_f32_16x16x32_bf16(a, b1, acc[m][1], 0, 0, 0);
      }
    }
    float pr[4][4];
#pragma unroll
    for (int m = 0; m < 4; ++m)
#pragma unroll
      for (int r2 = 0; r2 < 4; ++r2) pr[m][r2] = 0.f;
#pragma unroll
    for (int n = 0; n < 2; ++n) {
      int o = w * 32 + n * 16 + lr;
      float b3 = bc1[o], wc = Wc2[o];
#pragma unroll
      for (int m = 0; m < 4; ++m)
#pragma unroll
        for (int r2 = 0; r2 < 4; ++r2)
          pr[m][r2] += silu_f(acc[m][n][r2] + b3) * wc;
    }
#pragma unroll
    for (int m = 0; m < 4; ++m)
#pragma unroll
      for (int r2 = 0; r2 < 4; ++r2) {
        float v = pr[m][r2];
        v += __shfl_xor(v, 1); v += __shfl_xor(v, 2);
        v += __shfl_xor(v, 4); v += __shfl_xor(v, 8);
        pr[m][r2] = v;
      }
    if (lr == 0) {
#pragma unroll
      for (int m = 0; m < 4; ++m)
#pragma unroll
        for (int r2 = 0; r2 < 4; ++r2)
          swred[w][m * 16 + lg * 4 + r2] = pr[m][r2];
    }
  }
  __syncthreads();

  // ---- segmented aggregation (dst-sorted), all 4 waves: quarter of 16 edges each,
  //      paired columns via u32 LDS reads ----
  const int nv = min(64, E - tbase);
  {
    int cp = tid & 63, qt = tid >> 6;   // col-pair 0..63, quarter 0..3
    int c0 = cp * 2;
    int e0 = qt * 16;
    int nvh = min(16, nv - e0);
    if (nvh > 0) {
      float r0 = 0.f, r1 = 0.f;
      int prev = sdst[e0];
#pragma unroll 4
      for (int j = 0; j < nvh; ++j) {
        int e = e0 + j;
        int d = sdst[e];
        uint32_t u = *(const uint32_t*)(&Ms[msoff(e, c0)]);
        if (d != prev) {
          atomicAdd(&aggH[(size_t)prev * 128 + c0],     r0);
          atomicAdd(&aggH[(size_t)prev * 128 + c0 + 1], r1);
          r0 = 0.f; r1 = 0.f; prev = d;
        }
        float lo, hi; unpack2(u, lo, hi);
        r0 += lo; r1 += hi;
      }
      atomicAdd(&aggH[(size_t)prev * 128 + c0],     r0);
      atomicAdd(&aggH[(size_t)prev * 128 + c0 + 1], r1);
    }
  }
  // coord agg: threads 0..11 (3 coords x 4 quarters)
  if (tid < 12) {
    int c3 = tid % 3, qt = tid / 3;
    int e0 = qt * 16;
    int nvh = min(16, nv - e0);
    if (nvh > 0) {
      float run = 0.f;
      int prev = sdst[e0];
#pragma unroll 4
      for (int j = 0; j < nvh; ++j) {
        int e = e0 + j;
        int d = sdst[e];
        float cwv = swred[0][e] + swred[1][e] + swred[2][e] + swred[3][e];
        if (d != prev) {
          atomicAdd(&coordX[(size_t)prev * 3 + c3], run);
          run = 0.f; prev = d;
        }
        run += sdif[e][c3] * cwv;
      }
      atomicAdd(&coordX[(size_t)prev * 3 + c3], run);
    }
  }
}

// ---- fused node kernel v2: 64 nodes/block, 4 waves, wave owns 16 rows;
//      GEMM n1 A direct-from-global (no In staging); hp aliases U; LDS ~34KB ----
__global__ __launch_bounds__(256) void node_kernel(
    const float* __restrict__ h, const float* __restrict__ x,
    const float* __restrict__ bn1, const float* __restrict__ bn2,
    const float* __restrict__ gamma, const float* __restrict__ beta,
    const unsigned short* __restrict__ N1b, const unsigned short* __restrict__ N2b,
    float* __restrict__ aggH, float* __restrict__ coordX,
    const int* __restrict__ deg, int N) {
  __shared__ __align__(16) float hp[64 * 132];          // 33792B; first 17408B alias U
  __shared__ float scnt[64];
  unsigned short* U = (unsigned short*)hp;              // U[64][136] bf16

  const int tid  = threadIdx.x;
  const int base = blockIdx.x * 64;
  const int w    = tid >> 6;
  const int lane = tid & 63;
  const int lg   = lane >> 4, lr = lane & 15;
  const int w16  = w * 16;

  if (tid < 64) {
    int n = base + tid;
    scnt[tid] = (n < N) ? fmaxf((float)deg[n], 1.0f) : 1.0f;
  }
  __syncthreads();

  // per-lane A row (wave-local band) + agg scale
  int arow = base + w16 + lr; if (arow >= N) arow = N - 1;
  const float sc = 1.0f / scnt[w16 + lr];

  // GEMM n1: [h|agg/cnt] @ Wn1^T (+bn1), silu -> U ; A direct from global
  {
    f32x4 acc[8];
#pragma unroll
    for (int n = 0; n < 8; ++n) { f32x4 z = {0.f,0.f,0.f,0.f}; acc[n] = z; }
#pragma unroll
    for (int k0 = 0; k0 < 8; ++k0) {
      const float* p = (k0 < 4) ? (h    + (size_t)arow * 128 + k0 * 32 + lg * 8)
                                : (aggH + (size_t)arow * 128 + (k0 - 4) * 32 + lg * 8);
      float s = (k0 < 4) ? 1.0f : sc;
      float4 fa = *(const float4*)p;
      float4 fb = *(const float4*)(p + 4);
      union { uint32_t u[4]; bf16x8 v; } cv;
      cv.u[0] = cvtpk2(fa.x * s, fa.y * s);
      cv.u[1] = cvtpk2(fa.z * s, fa.w * s);
      cv.u[2] = cvtpk2(fb.x * s, fb.y * s);
      cv.u[3] = cvtpk2(fb.z * s, fb.w * s);
#pragma unroll
      for (int n = 0; n < 8; ++n) {
        bf16x8 b = *(const bf16x8*)(N1b + ((n * 16 + lr) << 8) + k0 * 32 + lg * 8);
        acc[n] = __builtin_amdgcn_mfma_f32_16x16x32_bf16(cv.v, b, acc[n], 0, 0, 0);
      }
    }
#pragma unroll
    for (int n = 0; n < 8; ++n) {
      int o = n * 16 + lr;
      float b1 = bn1[o];
#pragma unroll
      for (int r = 0; r < 4; ++r) {
        int me = lg * 4 + r;
        U[(size_t)(w16 + me) * 136 + o] = f2bf(silu_f(acc[n][r] + b1));
      }
    }
  }
  // no barrier needed: U rows are wave-local (written & read by same wave)

  // GEMM n2: U @ Wn2^T (+bn2 +h) -> hp (f32; aliases U, so barrier first)
  {
    f32x4 acc[8];
#pragma unroll
    for (int n = 0; n < 8; ++n) { f32x4 z = {0.f,0.f,0.f,0.f}; acc[n] = z; }
#pragma unroll
    for (int k0 = 0; k0 < 4; ++k0) {
      bf16x8 a = *(const bf16x8*)(&U[(size_t)(w16 + lr) * 136 + k0 * 32 + lg * 8]);
#pragma unroll
      for (int n = 0; n < 8; ++n) {
        bf16x8 b = *(const bf16x8*)(N2b + ((n * 16 + lr) << 7) + k0 * 32 + lg * 8);
        acc[n] = __builtin_amdgcn_mfma_f32_16x16x32_bf16(a, b, acc[n], 0, 0, 0);
      }
    }
    __syncthreads();   // ALL waves done reading U before hp overwrites it
#pragma unroll
    for (int n = 0; n < 8; ++n) {
      int o = n * 16 + lr;
      float b2 = bn2[o];
#pragma unroll
      for (int r = 0; r < 4; ++r) {
        int me = w16 + lg * 4 + r;
        int ng = base + me; if (ng >= N) ng = N - 1;
        hp[(size_t)me * 132 + o] = acc[n][r] + b2 + h[(size_t)ng * 128 + o];
      }
    }
  }
  __syncthreads();

  // LayerNorm: 4 threads per row, column map o = j*4+q (conflict-free banks)
  {
    int r = tid >> 2, qq = tid & 3;
    int ng = base + r;
    float s = 0.f, s2 = 0.f;
#pragma unroll
    for (int j = 0; j < 32; ++j) {
      float v = hp[(size_t)r * 132 + j * 4 + qq];
      s += v; s2 += v * v;
    }
    s  += __shfl_xor(s, 1);  s  += __shfl_xor(s, 2);
    s2 += __shfl_xor(s2, 1); s2 += __shfl_xor(s2, 2);
    float mu  = s * (1.0f / 128.0f);
    float var = s2 * (1.0f / 128.0f) - mu * mu;
    float rs  = rsqrtf(var + 1e-5f);
    if (ng < N) {
#pragma unroll
      for (int j = 0; j < 32; ++j) {
        int o = j * 4 + qq;
        float v = (hp[(size_t)r * 132 + o] - mu) * rs * gamma[o] + beta[o];
        aggH[(size_t)ng * 128 + o] = v;
      }
    }
  }

  if (tid < 192) {
    int i = tid / 3, c = tid % 3;
    int n2 = base + i;
    if (n2 < N) {
      size_t off = (size_t)n2 * 3 + c;
      coordX[off] = x[off] + coordX[off] / scnt[i];
    }
  }
}

extern "C" void kernel_launch(void* const* d_in, const int* in_sizes, int n_in,
                              void* d_out, int out_size, void* d_ws, size_t ws_size,
                              hipStream_t stream) {
  const float* h    = (const float*)d_in[0];
  const float* x    = (const float*)d_in[1];
  const int*   ei   = (const int*)d_in[2];
  const float* We1  = (const float*)d_in[3];
  const float* be1  = (const float*)d_in[4];
  const float* We2  = (const float*)d_in[5];
  const float* be2  = (const float*)d_in[6];
  const float* Wn1  = (const float*)d_in[7];
  const float* bn1  = (const float*)d_in[8];
  const float* Wn2  = (const float*)d_in[9];
  const float* bn2  = (const float*)d_in[10];
  const float* Wc1  = (const float*)d_in[11];
  const float* bc1  = (const float*)d_in[12];
  const float* Wc2  = (const float*)d_in[13];
  const float* gamma = (const float*)d_in[14];
  const float* beta  = (const float*)d_in[15];

  int N = in_sizes[0] / 128;
  int E = in_sizes[2] / 2;

  float* aggH   = (float*)d_out;                       // N*128: agg accumulator -> h_out
  float* coordX = (float*)d_out + (size_t)N * 128;     // N*3:   coord accumulator -> x_out

  char* ws = (char*)d_ws;
  size_t off = 0;
  auto alloc = [&](size_t bytes) {
    char* p = ws + off;
    off = (off + bytes + 255) & ~(size_t)255;
    return p;
  };
  unsigned short* Ps     = (unsigned short*)alloc((size_t)N * 128 * 2);
  unsigned short* Pd     = (unsigned short*)alloc((size_t)N * 128 * 2);
  unsigned short* W1p    = (unsigned short*)alloc(256 * 128 * 2);
  unsigned short* W2b    = (unsigned short*)alloc(128 * 128 * 2);
  unsigned short* N1b    = (unsigned short*)alloc(128 * 256 * 2);
  unsigned short* N2b    = (unsigned short*)alloc(128 * 128 * 2);
  unsigned short* W3b    = (unsigned short*)alloc(128 * 128 * 2);
  float*          w1c    = (float*)alloc(128 * 4);
  int*            flag   = (int*)alloc(4);
  int*            deg    = (int*)alloc((size_t)N * 4);
  int*            offs   = (int*)alloc(((size_t)N + 1) * 4);
  int*            cursor = (int*)alloc((size_t)N * 4);
  int*            bsum   = (int*)alloc(256 * 4);
  int2*           sd_s   = (int2*)alloc((size_t)E * 8);
  (void)ws_size;

  int nb = (N + 255) / 256;   // N=50000 -> 196 (<=256 required by scanB)

  hipMemsetAsync(d_out, 0, (size_t)out_size * 4, stream);
  hipMemsetAsync(deg, 0, (size_t)N * 4, stream);

  prep_kernel<<<128, 256, 0, stream>>>(We1, We2, Wn1, Wn2, Wc1, ei,
                                       W1p, W2b, N1b, N2b, W3b, w1c, flag);
  hist_kernel<<<(E + 255) / 256, 256, 0, stream>>>(ei, flag, deg, E);
  scanA_kernel<<<nb, 256, 0, stream>>>(deg, offs, bsum, N);
  scanB_kernel<<<1, 256, 0, stream>>>(bsum, offs, nb, N);
  scanC_kernel<<<nb, 256, 0, stream>>>(bsum, offs, cursor, N);
  scatter_kernel<<<(E + 255) / 256, 256, 0, stream>>>(ei, flag, cursor, sd_s, E);
  proj_kernel<<<(N + 63) / 64, 256, 0, stream>>>(h, be1, W1p, Ps, Pd, N);
  edge_kernel<<<(E + 63) / 64, 256, 0, stream>>>(Ps, Pd, x, sd_s, w1c,
                                                 be2, bc1, Wc2, W2b, W3b,
                                                 aggH, coordX, E);
  node_kernel<<<(N + 63) / 64, 256, 0, stream>>>(h, x, bn1, bn2, gamma, beta, N1b, N2b,
                                                 aggH, coordX, deg, N);
}

// Round 13
// 381.657 us; speedup vs baseline: 1.0313x; 1.0313x over previous
//
#include <hip/hip_runtime.h>
#include <stdint.h>

using bf16x8 = __attribute__((ext_vector_type(8))) short;
using f32x4  = __attribute__((ext_vector_type(4))) float;

__device__ __forceinline__ unsigned short f2bf(float f) {
  uint32_t x = __float_as_uint(f);
  x += 0x7fffu + ((x >> 16) & 1u);
  return (unsigned short)(x >> 16);
}
__device__ __forceinline__ float bf2f(unsigned short u) {
  return __uint_as_float(((uint32_t)u) << 16);
}
__device__ __forceinline__ uint32_t cvtpk2(float lo, float hi) {
  uint32_t r;
  asm("v_cvt_pk_bf16_f32 %0, %1, %2" : "=v"(r) : "v"(lo), "v"(hi));
  return r;
}
__device__ __forceinline__ float silu_f(float v) {
  float e = __expf(-v);
  return v * __builtin_amdgcn_rcpf(1.0f + e);
}
__device__ __forceinline__ void unpack2(uint32_t u, float& lo, float& hi) {
  lo = __uint_as_float(u << 16);
  hi = __uint_as_float(u & 0xffff0000u);
}

// Ms rotated-swizzle addressing: row stride 136 ushort (272B, b128-aligned).
__device__ __forceinline__ int msoff(int row, int col) {
  return row * 136 + ((((col >> 3) + row * 4) & 15) << 3) + (col & 7);
}
__device__ __forceinline__ int msoff_slot(int row, int slot) {
  return row * 136 + (((slot + row * 4) & 15) << 3);
}

// ---- prep: weights -> bf16, W1p split layout, w1c column, flag sniff ----
__global__ void prep_kernel(const float* __restrict__ We1, const float* __restrict__ We2,
                            const float* __restrict__ Wn1, const float* __restrict__ Wn2,
                            const float* __restrict__ Wc1, const int* __restrict__ ei,
                            unsigned short* __restrict__ W1p, unsigned short* __restrict__ W2b,
                            unsigned short* __restrict__ N1b, unsigned short* __restrict__ N2b,
                            unsigned short* __restrict__ W3b, float* __restrict__ w1c,
                            int* __restrict__ flag) {
  int i = blockIdx.x * 256 + threadIdx.x;      // 0..32767
  if (i < 256 * 128) {
    int c = i >> 7, k = i & 127;
    W1p[i] = f2bf(We1[(size_t)(c & 127) * 257 + ((c >> 7) << 7) + k]);
    N1b[i] = f2bf(Wn1[i]);
  }
  if (i < 128 * 128) {
    W2b[i] = f2bf(We2[i]);
    W3b[i] = f2bf(Wc1[i]);
    N2b[i] = f2bf(Wn2[i]);
  }
  if (i < 128) w1c[i] = We1[i * 257 + 256];
  if (i == 0) {
    int allz = 1;
    for (int k = 0; k < 64; ++k) allz &= (ei[2 * k + 1] == 0);
    *flag = allz;   // 1 => int64 indices
  }
}

// ---- CSR-order build: hist + 3-kernel parallel scan + scatter (2 edges/thread) ----
__global__ void hist_kernel(const int* __restrict__ ei, const int* __restrict__ flag,
                            int* __restrict__ deg, int E) {
  int e0 = (blockIdx.x * 256 + threadIdx.x) * 2;
  if (e0 >= E) return;
  bool has1 = (e0 + 1 < E);
  int d0, d1 = 0;
  if (*flag) {
    const long long* p = (const long long*)ei + E + e0;
    d0 = (int)p[0]; if (has1) d1 = (int)p[1];
  } else {
    const int* p = ei + E + e0;
    d0 = p[0]; if (has1) d1 = p[1];
  }
  atomicAdd(&deg[d0], 1);
  if (has1) atomicAdd(&deg[d1], 1);
}

__global__ void scanA_kernel(const int* __restrict__ deg, int* __restrict__ offs,
                             int* __restrict__ bsum, int N) {
  __shared__ int sh[256];
  int t = threadIdx.x, idx = blockIdx.x * 256 + t;
  int v = (idx < N) ? deg[idx] : 0;
  sh[t] = v;
  __syncthreads();
#pragma unroll
  for (int d = 1; d < 256; d <<= 1) {
    int u = (t >= d) ? sh[t - d] : 0;
    __syncthreads();
    sh[t] += u;
    __syncthreads();
  }
  if (idx < N) offs[idx] = sh[t] - v;
  if (t == 255) bsum[blockIdx.x] = sh[255];
}

__global__ void scanB_kernel(int* __restrict__ bsum, int* __restrict__ offs,
                             int nb, int N) {
  __shared__ int sh[256];
  int t = threadIdx.x;
  int v = (t < nb) ? bsum[t] : 0;
  sh[t] = v;
  __syncthreads();
#pragma unroll
  for (int d = 1; d < 256; d <<= 1) {
    int u = (t >= d) ? sh[t - d] : 0;
    __syncthreads();
    sh[t] += u;
    __syncthreads();
  }
  bsum[t] = sh[t] - v;
  if (t == 255) offs[N] = sh[255];
}

__global__ void scanC_kernel(const int* __restrict__ bsum, int* __restrict__ offs,
                             int* __restrict__ cursor, int N) {
  int idx = blockIdx.x * 256 + threadIdx.x;
  if (idx < N) {
    int o = offs[idx] + bsum[blockIdx.x];
    offs[idx] = o;
    cursor[idx] = o;
  }
}

// scatter: dst-sorted packed (src,dst) pairs, 2 edges/thread
__global__ void scatter_kernel(const int* __restrict__ ei, const int* __restrict__ flag,
                               int* __restrict__ cursor, int2* __restrict__ sd_s, int E) {
  int e0 = (blockIdx.x * 256 + threadIdx.x) * 2;
  if (e0 >= E) return;
  int ne = min(2, E - e0);
  int ss[2], dd[2];
  if (*flag) {
    const long long* ps = (const long long*)ei + e0;
    const long long* pd = (const long long*)ei + E + e0;
    for (int j = 0; j < ne; ++j) { ss[j] = (int)ps[j]; dd[j] = (int)pd[j]; }
  } else {
    const int* ps = ei + e0;
    const int* pd = ei + E + e0;
    for (int j = 0; j < ne; ++j) { ss[j] = ps[j]; dd[j] = pd[j]; }
  }
  for (int j = 0; j < ne; ++j) {
    int pos = atomicAdd(&cursor[dd[j]], 1);
    int2 p; p.x = ss[j]; p.y = dd[j];
    sd_s[pos] = p;
  }
}

// ---- proj: Ps[n] = h[n]@Ws^T + be1 ; Pd[n] = h[n]@Wd^T  (bf16, split arrays) ----
__global__ __launch_bounds__(256) void proj_kernel(
    const float* __restrict__ h, const float* __restrict__ be1,
    const unsigned short* __restrict__ W1p,
    unsigned short* __restrict__ Ps, unsigned short* __restrict__ Pd, int N) {
  const int tid = threadIdx.x;
  const int base = blockIdx.x * 64;
  const int w = tid >> 6, lane = tid & 63, lg = lane >> 4, lr = lane & 15;

  f32x4 acc[4][4];
#pragma unroll
  for (int m = 0; m < 4; ++m)
#pragma unroll
    for (int n = 0; n < 4; ++n) { f32x4 z = {0.f,0.f,0.f,0.f}; acc[m][n] = z; }

#pragma unroll
  for (int k0 = 0; k0 < 4; ++k0) {
    bf16x8 b[4];
#pragma unroll
    for (int n = 0; n < 4; ++n)
      b[n] = *(const bf16x8*)(W1p + ((w * 64 + n * 16 + lr) << 7) + k0 * 32 + lg * 8);
#pragma unroll
    for (int m = 0; m < 4; ++m) {
      int row = base + m * 16 + lr; if (row >= N) row = N - 1;
      const float* p = h + (size_t)row * 128 + k0 * 32 + lg * 8;
      float4 fa = *(const float4*)p;
      float4 fb = *(const float4*)(p + 4);
      union { uint32_t u[4]; bf16x8 v; } cv;
      cv.u[0] = cvtpk2(fa.x, fa.y); cv.u[1] = cvtpk2(fa.z, fa.w);
      cv.u[2] = cvtpk2(fb.x, fb.y); cv.u[3] = cvtpk2(fb.z, fb.w);
#pragma unroll
      for (int n = 0; n < 4; ++n)
        acc[m][n] = __builtin_amdgcn_mfma_f32_16x16x32_bf16(cv.v, b[n], acc[m][n], 0, 0, 0);
    }
  }
#pragma unroll
  for (int n = 0; n < 4; ++n) {
    int o = w * 64 + n * 16 + lr;
    unsigned short* dstp = (o < 128) ? Ps : Pd;
    int oo = o & 127;
    float add = (o < 128) ? be1[o] : 0.f;    // fold be1 into Ps half
#pragma unroll
    for (int m = 0; m < 4; ++m)
#pragma unroll
      for (int r = 0; r < 4; ++r) {
        int row = base + m * 16 + lg * 4 + r;
        if (row < N) dstp[(size_t)row * 128 + oo] = f2bf(acc[m][n][r] + add);
      }
  }
}

// ---- fused edge kernel: 64 dst-sorted edges/block; gather Ps/Pd + combine,
//      GEMM2, GEMM3, segmented aggregation with complete-run plain stores ----
__global__ __launch_bounds__(256, 6) void edge_kernel(
    const unsigned short* __restrict__ Ps, const unsigned short* __restrict__ Pd,
    const float* __restrict__ x, const int2* __restrict__ sd_s,
    const int* __restrict__ offs,
    const float* __restrict__ w1c,
    const float* __restrict__ be2, const float* __restrict__ bc1,
    const float* __restrict__ Wc2,
    const unsigned short* __restrict__ W2b, const unsigned short* __restrict__ W3b,
    float* __restrict__ aggH, float* __restrict__ coordX, int E) {
  __shared__ __align__(16) unsigned short Ms[64 * 136];  // combine out, then Ms2
  __shared__ float swred[4][64];
  __shared__ int   ssrc[64], sdst[64];
  __shared__ float sds[64];
  __shared__ float sdif[64][3];
  __shared__ unsigned char sA[64], sB[64];   // run-completeness flags

  const int tid   = threadIdx.x;
  const int tbase = blockIdx.x * 64;
  const int w = tid >> 6, lane = tid & 63, lg = lane >> 4, lr = lane & 15;

  // phase 0: indices + geometry + completeness flags
  if (tid < 64) {
    int p0 = tbase + tid;
    int s = 0, d = 0;
    unsigned char fa = 0, fb = 0;
    if (p0 < E) {
      int2 p = sd_s[p0]; s = p.x; d = p.y;
      fa = (offs[d] == p0);          // this edge is dst's first edge globally
      fb = (offs[d + 1] == p0 + 1);  // this edge is dst's last edge globally
    }
    ssrc[tid] = s; sdst[tid] = d;
    sA[tid] = fa; sB[tid] = fb;
    float dx = x[s * 3 + 0] - x[d * 3 + 0];
    float dy = x[s * 3 + 1] - x[d * 3 + 1];
    float dz = x[s * 3 + 2] - x[d * 3 + 2];
    sdif[tid][0] = dx; sdif[tid][1] = dy; sdif[tid][2] = dz;
    sds[tid] = dx * dx + dy * dy + dz * dz;
  }
  __syncthreads();

  // ---- gather Ps[src]/Pd[dst], combine + silu -> Ms (2x2 chunks: low live-reg) ----
  {
    const float4* w4 = (const float4*)w1c;
#pragma unroll
    for (int ch = 0; ch < 2; ++ch) {
      uint4 av[2], bv[2];
#pragma unroll
      for (int it = 0; it < 2; ++it) {
        int idx = tid + (ch * 2 + it) * 256;   // 0..1023
        int e = idx >> 4, seg = idx & 15;
        av[it] = *(const uint4*)(Ps + (size_t)ssrc[e] * 128 + seg * 8);
        bv[it] = *(const uint4*)(Pd + (size_t)sdst[e] * 128 + seg * 8);
      }
#pragma unroll
      for (int it = 0; it < 2; ++it) {
        int idx = tid + (ch * 2 + it) * 256;
        int e = idx >> 4, seg = idx & 15;
        float dsv = sds[e];
        float4 wA = w4[seg * 2], wB = w4[seg * 2 + 1];
        float a0,a1,a2,a3,a4,a5,a6,a7, b0,b1,b2,b3,b4,b5,b6,b7;
        unpack2(((uint32_t*)&av[it])[0], a0, a1);
        unpack2(((uint32_t*)&av[it])[1], a2, a3);
        unpack2(((uint32_t*)&av[it])[2], a4, a5);
        unpack2(((uint32_t*)&av[it])[3], a6, a7);
        unpack2(((uint32_t*)&bv[it])[0], b0, b1);
        unpack2(((uint32_t*)&bv[it])[1], b2, b3);
        unpack2(((uint32_t*)&bv[it])[2], b4, b5);
        unpack2(((uint32_t*)&bv[it])[3], b6, b7);
        float v0 = silu_f(a0 + b0 + dsv * wA.x);
        float v1 = silu_f(a1 + b1 + dsv * wA.y);
        float v2 = silu_f(a2 + b2 + dsv * wA.z);
        float v3 = silu_f(a3 + b3 + dsv * wA.w);
        float v4 = silu_f(a4 + b4 + dsv * wB.x);
        float v5 = silu_f(a5 + b5 + dsv * wB.y);
        float v6 = silu_f(a6 + b6 + dsv * wB.z);
        float v7 = silu_f(a7 + b7 + dsv * wB.w);
        uint4 o;
        o.x = cvtpk2(v0, v1); o.y = cvtpk2(v2, v3);
        o.z = cvtpk2(v4, v5); o.w = cvtpk2(v6, v7);
        *(uint4*)(&Ms[msoff_slot(e, seg)]) = o;
      }
    }
  }
  __syncthreads();

  // ---- GEMM2: Ms @ We2^T (+be2), silu -> Ms2 (same arena) ----
  {
    f32x4 acc[4][2];
#pragma unroll
    for (int m = 0; m < 4; ++m) { f32x4 z = {0.f,0.f,0.f,0.f}; acc[m][0] = z; acc[m][1] = z; }
#pragma unroll
    for (int k0 = 0; k0 < 4; ++k0) {
      bf16x8 b0 = *(const bf16x8*)(W2b + ((w * 32 + lr)      << 7) + k0 * 32 + lg * 8);
      bf16x8 b1 = *(const bf16x8*)(W2b + ((w * 32 + 16 + lr) << 7) + k0 * 32 + lg * 8);
#pragma unroll
      for (int m = 0; m < 4; ++m) {
        int row = m * 16 + lr;
        bf16x8 a = *(const bf16x8*)(&Ms[msoff_slot(row, k0 * 4 + lg)]);
        acc[m][0] = __builtin_amdgcn_mfma_f32_16x16x32_bf16(a, b0, acc[m][0], 0, 0, 0);
        acc[m][1] = __builtin_amdgcn_mfma_f32_16x16x32_bf16(a, b1, acc[m][1], 0, 0, 0);
      }
    }
    uint32_t pk[4][2][2];
#pragma unroll
    for (int n = 0; n < 2; ++n) {
      int o = w * 32 + n * 16 + lr;
      float b2v = be2[o];
#pragma unroll
      for (int m = 0; m < 4; ++m)
#pragma unroll
        for (int r2 = 0; r2 < 4; r2 += 2)
          pk[m][n][r2 >> 1] = cvtpk2(silu_f(acc[m][n][r2] + b2v),
                                     silu_f(acc[m][n][r2 + 1] + b2v));
    }
    __syncthreads();   // all waves done READING Ms
#pragma unroll
    for (int n = 0; n < 2; ++n) {
      int o = w * 32 + n * 16 + lr;
#pragma unroll
      for (int m = 0; m < 4; ++m)
#pragma unroll
        for (int r2 = 0; r2 < 4; r2 += 2) {
          int row = m * 16 + lg * 4 + r2;
          uint32_t u = pk[m][n][r2 >> 1];
          Ms[msoff(row, o)]     = (unsigned short)(u & 0xffffu);
          Ms[msoff(row + 1, o)] = (unsigned short)(u >> 16);
        }
    }
  }
  __syncthreads();

  // ---- GEMM3: Ms2 @ Wc1^T, silu, dot Wc2 -> swred ----
  {
    f32x4 acc[4][2];
#pragma unroll
    for (int m = 0; m < 4; ++m) { f32x4 z = {0.f,0.f,0.f,0.f}; acc[m][0] = z; acc[m][1] = z; }
#pragma unroll
    for (int k0 = 0; k0 < 4; ++k0) {
      bf16x8 b0 = *(const bf16x8*)(W3b + ((w * 32 + lr)      << 7) + k0 * 32 + lg * 8);
      bf16x8 b1 = *(const bf16x8*)(W3b + ((w * 32 + 16 + lr) << 7) + k0 * 32 + lg * 8);
#pragma unroll
      for (int m = 0; m < 4; ++m) {
        int row = m * 16 + lr;
        bf16x8 a = *(const bf16x8*)(&Ms[msoff_slot(row, k0 * 4 + lg)]);
        acc[m][0] = __builtin_amdgcn_mfma_f32_16x16x32_bf16(a, b0, acc[m][0], 0, 0, 0);
        acc[m][1] = __builtin_amdgcn_mfma_f32_16x16x32_bf16(a, b1, acc[m][1], 0, 0, 0);
      }
    }
    float pr[4][4];
#pragma unroll
    for (int m = 0; m < 4; ++m)
#pragma unroll
      for (int r2 = 0; r2 < 4; ++r2) pr[m][r2] = 0.f;
#pragma unroll
    for (int n = 0; n < 2; ++n) {
      int o = w * 32 + n * 16 + lr;
      float b3 = bc1[o], wc = Wc2[o];
#pragma unroll
      for (int m = 0; m < 4; ++m)
#pragma unroll
        for (int r2 = 0; r2 < 4; ++r2)
          pr[m][r2] += silu_f(acc[m][n][r2] + b3) * wc;
    }
#pragma unroll
    for (int m = 0; m < 4; ++m)
#pragma unroll
      for (int r2 = 0; r2 < 4; ++r2) {
        float v = pr[m][r2];
        v += __shfl_xor(v, 1); v += __shfl_xor(v, 2);
        v += __shfl_xor(v, 4); v += __shfl_xor(v, 8);
        pr[m][r2] = v;
      }
    if (lr == 0) {
#pragma unroll
      for (int m = 0; m < 4; ++m)
#pragma unroll
        for (int r2 = 0; r2 < 4; ++r2)
          swred[w][m * 16 + lg * 4 + r2] = pr[m][r2];
    }
  }
  __syncthreads();

  // ---- segmented aggregation (dst-sorted), 2 halves x 64 col-pairs;
  //      complete runs (all of dst's edges in this walk) -> plain stores ----
  const int nv = min(64, E - tbase);
  if (tid < 128) {
    int cp = tid & 63, hf = tid >> 6;
    int c0 = cp * 2;
    int e0 = hf * 32;
    int nvh = min(32, nv - e0);
    if (nvh > 0) {
      float r0 = 0.f, r1 = 0.f;
      int prev = sdst[e0];
      int es = e0;
#pragma unroll 4
      for (int j = 0; j < nvh; ++j) {
        int e = e0 + j;
        int d = sdst[e];
        uint32_t u = *(const uint32_t*)(&Ms[msoff(e, c0)]);
        if (d != prev) {
          float* a0 = &aggH[(size_t)prev * 128 + c0];
          if (sA[es] && sB[e - 1]) { a0[0] = r0; a0[1] = r1; }
          else { atomicAdd(a0, r0); atomicAdd(a0 + 1, r1); }
          r0 = 0.f; r1 = 0.f; prev = d; es = e;
        }
        float lo, hi; unpack2(u, lo, hi);
        r0 += lo; r1 += hi;
      }
      float* a0 = &aggH[(size_t)prev * 128 + c0];
      if (sA[es] && sB[e0 + nvh - 1]) { a0[0] = r0; a0[1] = r1; }
      else { atomicAdd(a0, r0); atomicAdd(a0 + 1, r1); }
    }
  } else if (tid >= 192 && tid < 198) {
    int t6 = tid - 192;
    int c3 = t6 % 3, hf = t6 / 3;
    int e0 = hf * 32;
    int nvh = min(32, nv - e0);
    if (nvh > 0) {
      float run = 0.f;
      int prev = sdst[e0];
      int es = e0;
#pragma unroll 4
      for (int j = 0; j < nvh; ++j) {
        int e = e0 + j;
        int d = sdst[e];
        float cwv = swred[0][e] + swred[1][e] + swred[2][e] + swred[3][e];
        if (d != prev) {
          if (sA[es] && sB[e - 1]) coordX[(size_t)prev * 3 + c3] = run;
          else atomicAdd(&coordX[(size_t)prev * 3 + c3], run);
          run = 0.f; prev = d; es = e;
        }
        run += sdif[e][c3] * cwv;
      }
      if (sA[es] && sB[e0 + nvh - 1]) coordX[(size_t)prev * 3 + c3] = run;
      else atomicAdd(&coordX[(size_t)prev * 3 + c3], run);
    }
  }
}

// ---- fused node kernel (R11 version): 64 nodes/block; staged In; LN j*4+q ----
__global__ __launch_bounds__(256) void node_kernel(
    const float* __restrict__ h, const float* __restrict__ x,
    const float* __restrict__ bn1, const float* __restrict__ bn2,
    const float* __restrict__ gamma, const float* __restrict__ beta,
    const unsigned short* __restrict__ N1b, const unsigned short* __restrict__ N2b,
    float* __restrict__ aggH, float* __restrict__ coordX,
    const int* __restrict__ deg, int N) {
  __shared__ __align__(16) unsigned short In[64][264];
  __shared__ __align__(16) unsigned short U[64][136];
  __shared__ float scnt[64];

  const int tid  = threadIdx.x;
  const int base = blockIdx.x * 64;
  const int w    = tid >> 6;
  const int lane = tid & 63;
  const int lg   = lane >> 4, lr = lane & 15;
  const int w16  = w * 16;

  if (tid < 64) {
    int n = base + tid;
    scnt[tid] = (n < N) ? fmaxf((float)deg[n], 1.0f) : 1.0f;
  }
  __syncthreads();

#pragma unroll
  for (int it = 0; it < 8; ++it) {
    int idx = tid + it * 256;
    int i = idx >> 5, seg = idx & 31;
    int n = base + i; if (n >= N) n = N - 1;
    float sc = 1.0f;
    const float* p;
    if (seg < 16) { p = h + (size_t)n * 128 + seg * 8; }
    else          { p = aggH + (size_t)n * 128 + (seg - 16) * 8; sc = 1.0f / scnt[i]; }
    float4 a = *(const float4*)p;
    float4 b = *(const float4*)(p + 4);
    uint32_t u0 = cvtpk2(a.x * sc, a.y * sc);
    uint32_t u1 = cvtpk2(a.z * sc, a.w * sc);
    uint32_t u2 = cvtpk2(b.x * sc, b.y * sc);
    uint32_t u3 = cvtpk2(b.z * sc, b.w * sc);
    uint4 v = {u0, u1, u2, u3};
    *(uint4*)&In[i][seg * 8] = v;
  }
  __syncthreads();

  {
    f32x4 acc[8];
#pragma unroll
    for (int n = 0; n < 8; ++n) { f32x4 z = {0.f,0.f,0.f,0.f}; acc[n] = z; }
#pragma unroll
    for (int k0 = 0; k0 < 8; ++k0) {
      bf16x8 a = *(const bf16x8*)(&In[w16 + lr][k0 * 32 + lg * 8]);
#pragma unroll
      for (int n = 0; n < 8; ++n) {
        bf16x8 b = *(const bf16x8*)(N1b + ((n * 16 + lr) << 8) + k0 * 32 + lg * 8);
        acc[n] = __builtin_amdgcn_mfma_f32_16x16x32_bf16(a, b, acc[n], 0, 0, 0);
      }
    }
#pragma unroll
    for (int n = 0; n < 8; ++n) {
      int o = n * 16 + lr;
      float b1 = bn1[o];
#pragma unroll
      for (int r = 0; r < 4; ++r) {
        int me = lg * 4 + r;
        U[w16 + me][o] = f2bf(silu_f(acc[n][r] + b1));
      }
    }
  }

  float* hp = (float*)&In[0][0];   // stride 132 f32
  {
    f32x4 acc[8];
#pragma unroll
    for (int n = 0; n < 8; ++n) { f32x4 z = {0.f,0.f,0.f,0.f}; acc[n] = z; }
#pragma unroll
    for (int k0 = 0; k0 < 4; ++k0) {
      bf16x8 a = *(const bf16x8*)(&U[w16 + lr][k0 * 32 + lg * 8]);
#pragma unroll
      for (int n = 0; n < 8; ++n) {
        bf16x8 b = *(const bf16x8*)(N2b + ((n * 16 + lr) << 7) + k0 * 32 + lg * 8);
        acc[n] = __builtin_amdgcn_mfma_f32_16x16x32_bf16(a, b, acc[n], 0, 0, 0);
      }
    }
#pragma unroll
    for (int n = 0; n < 8; ++n) {
      int o = n * 16 + lr;
      float b2 = bn2[o];
#pragma unroll
      for (int r = 0; r < 4; ++r) {
        int me = w16 + lg * 4 + r;
        int ng = base + me; if (ng >= N) ng = N - 1;
        hp[(size_t)me * 132 + o] = acc[n][r] + b2 + h[(size_t)ng * 128 + o];
      }
    }
  }
  __syncthreads();

  // LayerNorm: 4 threads per row, column map o = j*4+q (conflict-free banks)
  {
    int r = tid >> 2, q = tid & 3;
    int ng = base + r;
    float s = 0.f, s2 = 0.f;
#pragma unroll
    for (int j = 0; j < 32; ++j) {
      float v = hp[(size_t)r * 132 + j * 4 + q];
      s += v; s2 += v * v;
    }
    s  += __shfl_xor(s, 1);  s  += __shfl_xor(s, 2);
    s2 += __shfl_xor(s2, 1); s2 += __shfl_xor(s2, 2);
    float mu  = s * (1.0f / 128.0f);
    float var = s2 * (1.0f / 128.0f) - mu * mu;
    float rs  = rsqrtf(var + 1e-5f);
    if (ng < N) {
#pragma unroll
      for (int j = 0; j < 32; ++j) {
        int o = j * 4 + q;
        float v = (hp[(size_t)r * 132 + o] - mu) * rs * gamma[o] + beta[o];
        aggH[(size_t)ng * 128 + o] = v;
      }
    }
  }

  if (tid < 192) {
    int i = tid / 3, c = tid % 3;
    int n2 = base + i;
    if (n2 < N) {
      size_t off = (size_t)n2 * 3 + c;
      coordX[off] = x[off] + coordX[off] / scnt[i];
    }
  }
}

extern "C" void kernel_launch(void* const* d_in, const int* in_sizes, int n_in,
                              void* d_out, int out_size, void* d_ws, size_t ws_size,
                              hipStream_t stream) {
  const float* h    = (const float*)d_in[0];
  const float* x    = (const float*)d_in[1];
  const int*   ei   = (const int*)d_in[2];
  const float* We1  = (const float*)d_in[3];
  const float* be1  = (const float*)d_in[4];
  const float* We2  = (const float*)d_in[5];
  const float* be2  = (const float*)d_in[6];
  const float* Wn1  = (const float*)d_in[7];
  const float* bn1  = (const float*)d_in[8];
  const float* Wn2  = (const float*)d_in[9];
  const float* bn2  = (const float*)d_in[10];
  const float* Wc1  = (const float*)d_in[11];
  const float* bc1  = (const float*)d_in[12];
  const float* Wc2  = (const float*)d_in[13];
  const float* gamma = (const float*)d_in[14];
  const float* beta  = (const float*)d_in[15];

  int N = in_sizes[0] / 128;
  int E = in_sizes[2] / 2;

  float* aggH   = (float*)d_out;                       // N*128: agg accumulator -> h_out
  float* coordX = (float*)d_out + (size_t)N * 128;     // N*3:   coord accumulator -> x_out

  char* ws = (char*)d_ws;
  size_t off = 0;
  auto alloc = [&](size_t bytes) {
    char* p = ws + off;
    off = (off + bytes + 255) & ~(size_t)255;
    return p;
  };
  unsigned short* Ps     = (unsigned short*)alloc((size_t)N * 128 * 2);
  unsigned short* Pd     = (unsigned short*)alloc((size_t)N * 128 * 2);
  unsigned short* W1p    = (unsigned short*)alloc(256 * 128 * 2);
  unsigned short* W2b    = (unsigned short*)alloc(128 * 128 * 2);
  unsigned short* N1b    = (unsigned short*)alloc(128 * 256 * 2);
  unsigned short* N2b    = (unsigned short*)alloc(128 * 128 * 2);
  unsigned short* W3b    = (unsigned short*)alloc(128 * 128 * 2);
  float*          w1c    = (float*)alloc(128 * 4);
  int*            flag   = (int*)alloc(4);
  int*            deg    = (int*)alloc((size_t)N * 4);
  int*            offs   = (int*)alloc(((size_t)N + 1) * 4);
  int*            cursor = (int*)alloc((size_t)N * 4);
  int*            bsum   = (int*)alloc(256 * 4);
  int2*           sd_s   = (int2*)alloc((size_t)E * 8);
  (void)ws_size;

  int nb = (N + 255) / 256;   // N=50000 -> 196 (<=256 required by scanB)
  int epairs = (E + 1) / 2;

  hipMemsetAsync(d_out, 0, (size_t)out_size * 4, stream);
  hipMemsetAsync(deg, 0, (size_t)N * 4, stream);

  prep_kernel<<<128, 256, 0, stream>>>(We1, We2, Wn1, Wn2, Wc1, ei,
                                       W1p, W2b, N1b, N2b, W3b, w1c, flag);
  hist_kernel<<<(epairs + 255) / 256, 256, 0, stream>>>(ei, flag, deg, E);
  scanA_kernel<<<nb, 256, 0, stream>>>(deg, offs, bsum, N);
  scanB_kernel<<<1, 256, 0, stream>>>(bsum, offs, nb, N);
  scanC_kernel<<<nb, 256, 0, stream>>>(bsum, offs, cursor, N);
  scatter_kernel<<<(epairs + 255) / 256, 256, 0, stream>>>(ei, flag, cursor, sd_s, E);
  proj_kernel<<<(N + 63) / 64, 256, 0, stream>>>(h, be1, W1p, Ps, Pd, N);
  edge_kernel<<<(E + 63) / 64, 256, 0, stream>>>(Ps, Pd, x, sd_s, offs, w1c,
                                                 be2, bc1, Wc2, W2b, W3b,
                                                 aggH, coordX, E);
  node_kernel<<<(N + 63) / 64, 256, 0, stream>>>(h, x, bn1, bn2, gamma, beta, N1b, N2b,
                                                 aggH, coordX, deg, N);
}

// Round 14
// 378.305 us; speedup vs baseline: 1.0405x; 1.0089x over previous
//
#include <hip/hip_runtime.h>
#include <stdint.h>

using bf16x8 = __attribute__((ext_vector_type(8))) short;
using f32x4  = __attribute__((ext_vector_type(4))) float;

__device__ __forceinline__ unsigned short f2bf(float f) {
  uint32_t x = __float_as_uint(f);
  x += 0x7fffu + ((x >> 16) & 1u);
  return (unsigned short)(x >> 16);
}
__device__ __forceinline__ float bf2f(unsigned short u) {
  return __uint_as_float(((uint32_t)u) << 16);
}
__device__ __forceinline__ uint32_t cvtpk2(float lo, float hi) {
  uint32_t r;
  asm("v_cvt_pk_bf16_f32 %0, %1, %2" : "=v"(r) : "v"(lo), "v"(hi));
  return r;
}
__device__ __forceinline__ float silu_f(float v) {
  float e = __expf(-v);
  return v * __builtin_amdgcn_rcpf(1.0f + e);
}
__device__ __forceinline__ void unpack2(uint32_t u, float& lo, float& hi) {
  lo = __uint_as_float(u << 16);
  hi = __uint_as_float(u & 0xffff0000u);
}

// Ms rotated-swizzle addressing: row stride 136 ushort (272B, b128-aligned).
__device__ __forceinline__ int msoff(int row, int col) {
  return row * 136 + ((((col >> 3) + row * 4) & 15) << 3) + (col & 7);
}
__device__ __forceinline__ int msoff_slot(int row, int slot) {
  return row * 136 + (((slot + row * 4) & 15) << 3);
}

// per-block self-sniff of edge_index dtype (1 => int64). All blocks read the
// same first 64 odd words -> consistent result; L2-hit after first block.
__device__ __forceinline__ int sniff_int64(const int* __restrict__ ei, int E,
                                           int* sflag_lds) {
  if (threadIdx.x == 0) {
    int allz = 1;
    int kk = (E < 32) ? E : 32;
    for (int k = 0; k < kk; ++k) allz &= (ei[2 * k + 1] == 0);
    *sflag_lds = allz;
  }
  __syncthreads();
  return *sflag_lds;
}

// ---- hist: 2 edges/thread, self-sniffed decode ----
__global__ void hist_kernel(const int* __restrict__ ei, int* __restrict__ deg, int E) {
  __shared__ int sflag;
  int f = sniff_int64(ei, E, &sflag);
  int e0 = (blockIdx.x * 256 + threadIdx.x) * 2;
  if (e0 >= E) return;
  bool has1 = (e0 + 1 < E);
  int d0, d1 = 0;
  if (f) {
    const long long* p = (const long long*)ei + E + e0;
    d0 = (int)p[0]; if (has1) d1 = (int)p[1];
  } else {
    const int* p = ei + E + e0;
    d0 = p[0]; if (has1) d1 = p[1];
  }
  atomicAdd(&deg[d0], 1);
  if (has1) atomicAdd(&deg[d1], 1);
}

// ---- scanA + weight-prep duty on blocks 0..127 ----
__global__ void scanA_kernel(const int* __restrict__ deg, int* __restrict__ offs,
                             int* __restrict__ bsum, int N,
                             const float* __restrict__ We1, const float* __restrict__ We2,
                             const float* __restrict__ Wn1, const float* __restrict__ Wn2,
                             const float* __restrict__ Wc1,
                             unsigned short* __restrict__ W1p, unsigned short* __restrict__ W2b,
                             unsigned short* __restrict__ N1b, unsigned short* __restrict__ N2b,
                             unsigned short* __restrict__ W3b, float* __restrict__ w1c) {
  __shared__ int sh[256];
  int t = threadIdx.x, idx = blockIdx.x * 256 + t;
  int v = (idx < N) ? deg[idx] : 0;
  sh[t] = v;
  __syncthreads();
#pragma unroll
  for (int d = 1; d < 256; d <<= 1) {
    int u = (t >= d) ? sh[t - d] : 0;
    __syncthreads();
    sh[t] += u;
    __syncthreads();
  }
  if (idx < N) offs[idx] = sh[t] - v;
  if (t == 255) bsum[blockIdx.x] = sh[255];

  // weight prep (independent work; outputs consumed only by proj/edge/node)
  if (blockIdx.x < 128) {
    int i = blockIdx.x * 256 + t;   // 0..32767
    {
      int c = i >> 7, k = i & 127;
      W1p[i] = f2bf(We1[(size_t)(c & 127) * 257 + ((c >> 7) << 7) + k]);
      N1b[i] = f2bf(Wn1[i]);
    }
    if (i < 128 * 128) {
      W2b[i] = f2bf(We2[i]);
      W3b[i] = f2bf(Wc1[i]);
      N2b[i] = f2bf(Wn2[i]);
    }
    if (i < 128) w1c[i] = We1[i * 257 + 256];
  }
}

__global__ void scanB_kernel(int* __restrict__ bsum, int* __restrict__ offs,
                             int nb, int N) {
  __shared__ int sh[256];
  int t = threadIdx.x;
  int v = (t < nb) ? bsum[t] : 0;
  sh[t] = v;
  __syncthreads();
#pragma unroll
  for (int d = 1; d < 256; d <<= 1) {
    int u = (t >= d) ? sh[t - d] : 0;
    __syncthreads();
    sh[t] += u;
    __syncthreads();
  }
  bsum[t] = sh[t] - v;
  if (t == 255) offs[N] = sh[255];
}

__global__ void scanC_kernel(const int* __restrict__ bsum, int* __restrict__ offs,
                             int* __restrict__ cursor, int N) {
  int idx = blockIdx.x * 256 + threadIdx.x;
  if (idx < N) {
    int o = offs[idx] + bsum[blockIdx.x];
    offs[idx] = o;
    cursor[idx] = o;
  }
}

// ---- scatter: dst-sorted packed (src,dst) pairs, 2 edges/thread, self-sniff ----
__global__ void scatter_kernel(const int* __restrict__ ei, int* __restrict__ cursor,
                               int2* __restrict__ sd_s, int E) {
  __shared__ int sflag;
  int f = sniff_int64(ei, E, &sflag);
  int e0 = (blockIdx.x * 256 + threadIdx.x) * 2;
  if (e0 >= E) return;
  int ne = min(2, E - e0);
  int ss[2], dd[2];
  if (f) {
    const long long* ps = (const long long*)ei + e0;
    const long long* pd = (const long long*)ei + E + e0;
    for (int j = 0; j < ne; ++j) { ss[j] = (int)ps[j]; dd[j] = (int)pd[j]; }
  } else {
    const int* ps = ei + e0;
    const int* pd = ei + E + e0;
    for (int j = 0; j < ne; ++j) { ss[j] = ps[j]; dd[j] = pd[j]; }
  }
  for (int j = 0; j < ne; ++j) {
    int pos = atomicAdd(&cursor[dd[j]], 1);
    int2 p; p.x = ss[j]; p.y = dd[j];
    sd_s[pos] = p;
  }
}

// ---- proj: Ps[n] = h[n]@Ws^T + be1 ; Pd[n] = h[n]@Wd^T  (bf16, split arrays) ----
__global__ __launch_bounds__(256) void proj_kernel(
    const float* __restrict__ h, const float* __restrict__ be1,
    const unsigned short* __restrict__ W1p,
    unsigned short* __restrict__ Ps, unsigned short* __restrict__ Pd, int N) {
  const int tid = threadIdx.x;
  const int base = blockIdx.x * 64;
  const int w = tid >> 6, lane = tid & 63, lg = lane >> 4, lr = lane & 15;

  f32x4 acc[4][4];
#pragma unroll
  for (int m = 0; m < 4; ++m)
#pragma unroll
    for (int n = 0; n < 4; ++n) { f32x4 z = {0.f,0.f,0.f,0.f}; acc[m][n] = z; }

#pragma unroll
  for (int k0 = 0; k0 < 4; ++k0) {
    bf16x8 b[4];
#pragma unroll
    for (int n = 0; n < 4; ++n)
      b[n] = *(const bf16x8*)(W1p + ((w * 64 + n * 16 + lr) << 7) + k0 * 32 + lg * 8);
#pragma unroll
    for (int m = 0; m < 4; ++m) {
      int row = base + m * 16 + lr; if (row >= N) row = N - 1;
      const float* p = h + (size_t)row * 128 + k0 * 32 + lg * 8;
      float4 fa = *(const float4*)p;
      float4 fb = *(const float4*)(p + 4);
      union { uint32_t u[4]; bf16x8 v; } cv;
      cv.u[0] = cvtpk2(fa.x, fa.y); cv.u[1] = cvtpk2(fa.z, fa.w);
      cv.u[2] = cvtpk2(fb.x, fb.y); cv.u[3] = cvtpk2(fb.z, fb.w);
#pragma unroll
      for (int n = 0; n < 4; ++n)
        acc[m][n] = __builtin_amdgcn_mfma_f32_16x16x32_bf16(cv.v, b[n], acc[m][n], 0, 0, 0);
    }
  }
#pragma unroll
  for (int n = 0; n < 4; ++n) {
    int o = w * 64 + n * 16 + lr;
    unsigned short* dstp = (o < 128) ? Ps : Pd;
    int oo = o & 127;
    float add = (o < 128) ? be1[o] : 0.f;    // fold be1 into Ps half
#pragma unroll
    for (int m = 0; m < 4; ++m)
#pragma unroll
      for (int r = 0; r < 4; ++r) {
        int row = base + m * 16 + lg * 4 + r;
        if (row < N) dstp[(size_t)row * 128 + oo] = f2bf(acc[m][n][r] + add);
      }
  }
}

// ---- fused edge kernel: 64 dst-sorted edges/block; gather Ps/Pd + combine,
//      GEMM2, GEMM3, segmented aggregation.  8 blocks/CU (VGPR<=64, LDS 8x19968) ----
__global__ __launch_bounds__(256, 8) void edge_kernel(
    const unsigned short* __restrict__ Ps, const unsigned short* __restrict__ Pd,
    const float* __restrict__ x, const int2* __restrict__ sd_s,
    const float* __restrict__ w1c,
    const float* __restrict__ be2, const float* __restrict__ bc1,
    const float* __restrict__ Wc2,
    const unsigned short* __restrict__ W2b, const unsigned short* __restrict__ W3b,
    float* __restrict__ aggH, float* __restrict__ coordX, int E) {
  __shared__ __align__(16) unsigned short Ms[64 * 136];  // combine out, then Ms2
  __shared__ float swred[4][64];
  __shared__ int   ssrc[64], sdst[64];
  __shared__ float sds[64];
  __shared__ float sdif[64][3];

  const int tid   = threadIdx.x;
  const int tbase = blockIdx.x * 64;
  const int w = tid >> 6, lane = tid & 63, lg = lane >> 4, lr = lane & 15;

  // phase 0: indices + geometry (dst-sorted, coalesced int2 loads)
  if (tid < 64) {
    int p0 = tbase + tid;
    int s = 0, d = 0;
    if (p0 < E) { int2 p = sd_s[p0]; s = p.x; d = p.y; }
    ssrc[tid] = s; sdst[tid] = d;
    float dx = x[s * 3 + 0] - x[d * 3 + 0];
    float dy = x[s * 3 + 1] - x[d * 3 + 1];
    float dz = x[s * 3 + 2] - x[d * 3 + 2];
    sdif[tid][0] = dx; sdif[tid][1] = dy; sdif[tid][2] = dz;
    sds[tid] = dx * dx + dy * dy + dz * dz;
  }
  __syncthreads();

  // ---- gather Ps[src]/Pd[dst], combine + silu -> Ms (2x2 chunks: low live-reg) ----
  {
    const float4* w4 = (const float4*)w1c;
#pragma unroll
    for (int ch = 0; ch < 2; ++ch) {
      uint4 av[2], bv[2];
#pragma unroll
      for (int it = 0; it < 2; ++it) {
        int idx = tid + (ch * 2 + it) * 256;   // 0..1023
        int e = idx >> 4, seg = idx & 15;
        av[it] = *(const uint4*)(Ps + (size_t)ssrc[e] * 128 + seg * 8);
        bv[it] = *(const uint4*)(Pd + (size_t)sdst[e] * 128 + seg * 8);
      }
#pragma unroll
      for (int it = 0; it < 2; ++it) {
        int idx = tid + (ch * 2 + it) * 256;
        int e = idx >> 4, seg = idx & 15;
        float dsv = sds[e];
        float4 wA = w4[seg * 2], wB = w4[seg * 2 + 1];
        float a0,a1,a2,a3,a4,a5,a6,a7, b0,b1,b2,b3,b4,b5,b6,b7;
        unpack2(((uint32_t*)&av[it])[0], a0, a1);
        unpack2(((uint32_t*)&av[it])[1], a2, a3);
        unpack2(((uint32_t*)&av[it])[2], a4, a5);
        unpack2(((uint32_t*)&av[it])[3], a6, a7);
        unpack2(((uint32_t*)&bv[it])[0], b0, b1);
        unpack2(((uint32_t*)&bv[it])[1], b2, b3);
        unpack2(((uint32_t*)&bv[it])[2], b4, b5);
        unpack2(((uint32_t*)&bv[it])[3], b6, b7);
        float v0 = silu_f(a0 + b0 + dsv * wA.x);
        float v1 = silu_f(a1 + b1 + dsv * wA.y);
        float v2 = silu_f(a2 + b2 + dsv * wA.z);
        float v3 = silu_f(a3 + b3 + dsv * wA.w);
        float v4 = silu_f(a4 + b4 + dsv * wB.x);
        float v5 = silu_f(a5 + b5 + dsv * wB.y);
        float v6 = silu_f(a6 + b6 + dsv * wB.z);
        float v7 = silu_f(a7 + b7 + dsv * wB.w);
        uint4 o;
        o.x = cvtpk2(v0, v1); o.y = cvtpk2(v2, v3);
        o.z = cvtpk2(v4, v5); o.w = cvtpk2(v6, v7);
        *(uint4*)(&Ms[msoff_slot(e, seg)]) = o;
      }
    }
  }
  __syncthreads();

  // ---- GEMM2: Ms @ We2^T (+be2), silu -> Ms2 (same arena) ----
  {
    f32x4 acc[4][2];
#pragma unroll
    for (int m = 0; m < 4; ++m) { f32x4 z = {0.f,0.f,0.f,0.f}; acc[m][0] = z; acc[m][1] = z; }
#pragma unroll
    for (int k0 = 0; k0 < 4; ++k0) {
      bf16x8 b0 = *(const bf16x8*)(W2b + ((w * 32 + lr)      << 7) + k0 * 32 + lg * 8);
      bf16x8 b1 = *(const bf16x8*)(W2b + ((w * 32 + 16 + lr) << 7) + k0 * 32 + lg * 8);
#pragma unroll
      for (int m = 0; m < 4; ++m) {
        int row = m * 16 + lr;
        bf16x8 a = *(const bf16x8*)(&Ms[msoff_slot(row, k0 * 4 + lg)]);
        acc[m][0] = __builtin_amdgcn_mfma_f32_16x16x32_bf16(a, b0, acc[m][0], 0, 0, 0);
        acc[m][1] = __builtin_amdgcn_mfma_f32_16x16x32_bf16(a, b1, acc[m][1], 0, 0, 0);
      }
    }
    uint32_t pk[4][2][2];
#pragma unroll
    for (int n = 0; n < 2; ++n) {
      int o = w * 32 + n * 16 + lr;
      float b2v = be2[o];
#pragma unroll
      for (int m = 0; m < 4; ++m)
#pragma unroll
        for (int r2 = 0; r2 < 4; r2 += 2)
          pk[m][n][r2 >> 1] = cvtpk2(silu_f(acc[m][n][r2] + b2v),
                                     silu_f(acc[m][n][r2 + 1] + b2v));
    }
    __syncthreads();   // all waves done READING Ms
#pragma unroll
    for (int n = 0; n < 2; ++n) {
      int o = w * 32 + n * 16 + lr;
#pragma unroll
      for (int m = 0; m < 4; ++m)
#pragma unroll
        for (int r2 = 0; r2 < 4; r2 += 2) {
          int row = m * 16 + lg * 4 + r2;
          uint32_t u = pk[m][n][r2 >> 1];
          Ms[msoff(row, o)]     = (unsigned short)(u & 0xffffu);
          Ms[msoff(row + 1, o)] = (unsigned short)(u >> 16);
        }
    }
  }
  __syncthreads();

  // ---- GEMM3: Ms2 @ Wc1^T, silu, dot Wc2 -> swred ----
  {
    f32x4 acc[4][2];
#pragma unroll
    for (int m = 0; m < 4; ++m) { f32x4 z = {0.f,0.f,0.f,0.f}; acc[m][0] = z; acc[m][1] = z; }
#pragma unroll
    for (int k0 = 0; k0 < 4; ++k0) {
      bf16x8 b0 = *(const bf16x8*)(W3b + ((w * 32 + lr)      << 7) + k0 * 32 + lg * 8);
      bf16x8 b1 = *(const bf16x8*)(W3b + ((w * 32 + 16 + lr) << 7) + k0 * 32 + lg * 8);
#pragma unroll
      for (int m = 0; m < 4; ++m) {
        int row = m * 16 + lr;
        bf16x8 a = *(const bf16x8*)(&Ms[msoff_slot(row, k0 * 4 + lg)]);
        acc[m][0] = __builtin_amdgcn_mfma_f32_16x16x32_bf16(a, b0, acc[m][0], 0, 0, 0);
        acc[m][1] = __builtin_amdgcn_mfma_f32_16x16x32_bf16(a, b1, acc[m][1], 0, 0, 0);
      }
    }
    float pr[4][4];
#pragma unroll
    for (int m = 0; m < 4; ++m)
#pragma unroll
      for (int r2 = 0; r2 < 4; ++r2) pr[m][r2] = 0.f;
#pragma unroll
    for (int n = 0; n < 2; ++n) {
      int o = w * 32 + n * 16 + lr;
      float b3 = bc1[o], wc = Wc2[o];
#pragma unroll
      for (int m = 0; m < 4; ++m)
#pragma unroll
        for (int r2 = 0; r2 < 4; ++r2)
          pr[m][r2] += silu_f(acc[m][n][r2] + b3) * wc;
    }
#pragma unroll
    for (int m = 0; m < 4; ++m)
#pragma unroll
      for (int r2 = 0; r2 < 4; ++r2) {
        float v = pr[m][r2];
        v += __shfl_xor(v, 1); v += __shfl_xor(v, 2);
        v += __shfl_xor(v, 4); v += __shfl_xor(v, 8);
        pr[m][r2] = v;
      }
    if (lr == 0) {
#pragma unroll
      for (int m = 0; m < 4; ++m)
#pragma unroll
        for (int r2 = 0; r2 < 4; ++r2)
          swred[w][m * 16 + lg * 4 + r2] = pr[m][r2];
    }
  }
  __syncthreads();

  // ---- segmented aggregation (dst-sorted), 2 halves x 64 col-pairs ----
  const int nv = min(64, E - tbase);
  if (tid < 128) {
    int cp = tid & 63, hf = tid >> 6;
    int c0 = cp * 2;
    int e0 = hf * 32;
    int nvh = min(32, nv - e0);
    if (nvh > 0) {
      float r0 = 0.f, r1 = 0.f;
      int prev = sdst[e0];
#pragma unroll 4
      for (int j = 0; j < nvh; ++j) {
        int e = e0 + j;
        int d = sdst[e];
        uint32_t u = *(const uint32_t*)(&Ms[msoff(e, c0)]);
        if (d != prev) {
          atomicAdd(&aggH[(size_t)prev * 128 + c0],     r0);
          atomicAdd(&aggH[(size_t)prev * 128 + c0 + 1], r1);
          r0 = 0.f; r1 = 0.f; prev = d;
        }
        float lo, hi; unpack2(u, lo, hi);
        r0 += lo; r1 += hi;
      }
      atomicAdd(&aggH[(size_t)prev * 128 + c0],     r0);
      atomicAdd(&aggH[(size_t)prev * 128 + c0 + 1], r1);
    }
  } else if (tid >= 192 && tid < 198) {
    int t6 = tid - 192;
    int c3 = t6 % 3, hf = t6 / 3;
    int e0 = hf * 32;
    int nvh = min(32, nv - e0);
    if (nvh > 0) {
      float run = 0.f;
      int prev = sdst[e0];
#pragma unroll 4
      for (int j = 0; j < nvh; ++j) {
        int e = e0 + j;
        int d = sdst[e];
        float cwv = swred[0][e] + swred[1][e] + swred[2][e] + swred[3][e];
        if (d != prev) {
          atomicAdd(&coordX[(size_t)prev * 3 + c3], run);
          run = 0.f; prev = d;
        }
        run += sdif[e][c3] * cwv;
      }
      atomicAdd(&coordX[(size_t)prev * 3 + c3], run);
    }
  }
}

// ---- fused node kernel: 64 nodes/block; staged In; LN column map j*4+q ----
__global__ __launch_bounds__(256) void node_kernel(
    const float* __restrict__ h, const float* __restrict__ x,
    const float* __restrict__ bn1, const float* __restrict__ bn2,
    const float* __restrict__ gamma, const float* __restrict__ beta,
    const unsigned short* __restrict__ N1b, const unsigned short* __restrict__ N2b,
    float* __restrict__ aggH, float* __restrict__ coordX,
    const int* __restrict__ deg, int N) {
  __shared__ __align__(16) unsigned short In[64][264];
  __shared__ __align__(16) unsigned short U[64][136];
  __shared__ float scnt[64];

  const int tid  = threadIdx.x;
  const int base = blockIdx.x * 64;
  const int w    = tid >> 6;
  const int lane = tid & 63;
  const int lg   = lane >> 4, lr = lane & 15;
  const int w16  = w * 16;

  if (tid < 64) {
    int n = base + tid;
    scnt[tid] = (n < N) ? fmaxf((float)deg[n], 1.0f) : 1.0f;
  }
  __syncthreads();

#pragma unroll
  for (int it = 0; it < 8; ++it) {
    int idx = tid + it * 256;
    int i = idx >> 5, seg = idx & 31;
    int n = base + i; if (n >= N) n = N - 1;
    float sc = 1.0f;
    const float* p;
    if (seg < 16) { p = h + (size_t)n * 128 + seg * 8; }
    else          { p = aggH + (size_t)n * 128 + (seg - 16) * 8; sc = 1.0f / scnt[i]; }
    float4 a = *(const float4*)p;
    float4 b = *(const float4*)(p + 4);
    uint32_t u0 = cvtpk2(a.x * sc, a.y * sc);
    uint32_t u1 = cvtpk2(a.z * sc, a.w * sc);
    uint32_t u2 = cvtpk2(b.x * sc, b.y * sc);
    uint32_t u3 = cvtpk2(b.z * sc, b.w * sc);
    uint4 v = {u0, u1, u2, u3};
    *(uint4*)&In[i][seg * 8] = v;
  }
  __syncthreads();

  {
    f32x4 acc[8];
#pragma unroll
    for (int n = 0; n < 8; ++n) { f32x4 z = {0.f,0.f,0.f,0.f}; acc[n] = z; }
#pragma unroll
    for (int k0 = 0; k0 < 8; ++k0) {
      bf16x8 a = *(const bf16x8*)(&In[w16 + lr][k0 * 32 + lg * 8]);
#pragma unroll
      for (int n = 0; n < 8; ++n) {
        bf16x8 b = *(const bf16x8*)(N1b + ((n * 16 + lr) << 8) + k0 * 32 + lg * 8);
        acc[n] = __builtin_amdgcn_mfma_f32_16x16x32_bf16(a, b, acc[n], 0, 0, 0);
      }
    }
#pragma unroll
    for (int n = 0; n < 8; ++n) {
      int o = n * 16 + lr;
      float b1 = bn1[o];
#pragma unroll
      for (int r = 0; r < 4; ++r) {
        int me = lg * 4 + r;
        U[w16 + me][o] = f2bf(silu_f(acc[n][r] + b1));
      }
    }
  }

  float* hp = (float*)&In[0][0];   // stride 132 f32
  {
    f32x4 acc[8];
#pragma unroll
    for (int n = 0; n < 8; ++n) { f32x4 z = {0.f,0.f,0.f,0.f}; acc[n] = z; }
#pragma unroll
    for (int k0 = 0; k0 < 4; ++k0) {
      bf16x8 a = *(const bf16x8*)(&U[w16 + lr][k0 * 32 + lg * 8]);
#pragma unroll
      for (int n = 0; n < 8; ++n) {
        bf16x8 b = *(const bf16x8*)(N2b + ((n * 16 + lr) << 7) + k0 * 32 + lg * 8);
        acc[n] = __builtin_amdgcn_mfma_f32_16x16x32_bf16(a, b, acc[n], 0, 0, 0);
      }
    }
#pragma unroll
    for (int n = 0; n < 8; ++n) {
      int o = n * 16 + lr;
      float b2 = bn2[o];
#pragma unroll
      for (int r = 0; r < 4; ++r) {
        int me = w16 + lg * 4 + r;
        int ng = base + me; if (ng >= N) ng = N - 1;
        hp[(size_t)me * 132 + o] = acc[n][r] + b2 + h[(size_t)ng * 128 + o];
      }
    }
  }
  __syncthreads();

  // LayerNorm: 4 threads per row, column map o = j*4+q (conflict-free banks)
  {
    int r = tid >> 2, q = tid & 3;
    int ng = base + r;
    float s = 0.f, s2 = 0.f;
#pragma unroll
    for (int j = 0; j < 32; ++j) {
      float v = hp[(size_t)r * 132 + j * 4 + q];
      s += v; s2 += v * v;
    }
    s  += __shfl_xor(s, 1);  s  += __shfl_xor(s, 2);
    s2 += __shfl_xor(s2, 1); s2 += __shfl_xor(s2, 2);
    float mu  = s * (1.0f / 128.0f);
    float var = s2 * (1.0f / 128.0f) - mu * mu;
    float rs  = rsqrtf(var + 1e-5f);
    if (ng < N) {
#pragma unroll
      for (int j = 0; j < 32; ++j) {
        int o = j * 4 + q;
        float v = (hp[(size_t)r * 132 + o] - mu) * rs * gamma[o] + beta[o];
        aggH[(size_t)ng * 128 + o] = v;
      }
    }
  }

  if (tid < 192) {
    int i = tid / 3, c = tid % 3;
    int n2 = base + i;
    if (n2 < N) {
      size_t off = (size_t)n2 * 3 + c;
      coordX[off] = x[off] + coordX[off] / scnt[i];
    }
  }
}

extern "C" void kernel_launch(void* const* d_in, const int* in_sizes, int n_in,
                              void* d_out, int out_size, void* d_ws, size_t ws_size,
                              hipStream_t stream) {
  const float* h    = (const float*)d_in[0];
  const float* x    = (const float*)d_in[1];
  const int*   ei   = (const int*)d_in[2];
  const float* We1  = (const float*)d_in[3];
  const float* be1  = (const float*)d_in[4];
  const float* We2  = (const float*)d_in[5];
  const float* be2  = (const float*)d_in[6];
  const float* Wn1  = (const float*)d_in[7];
  const float* bn1  = (const float*)d_in[8];
  const float* Wn2  = (const float*)d_in[9];
  const float* bn2  = (const float*)d_in[10];
  const float* Wc1  = (const float*)d_in[11];
  const float* bc1  = (const float*)d_in[12];
  const float* Wc2  = (const float*)d_in[13];
  const float* gamma = (const float*)d_in[14];
  const float* beta  = (const float*)d_in[15];

  int N = in_sizes[0] / 128;
  int E = in_sizes[2] / 2;

  float* aggH   = (float*)d_out;                       // N*128: agg accumulator -> h_out
  float* coordX = (float*)d_out + (size_t)N * 128;     // N*3:   coord accumulator -> x_out

  char* ws = (char*)d_ws;
  size_t off = 0;
  auto alloc = [&](size_t bytes) {
    char* p = ws + off;
    off = (off + bytes + 255) & ~(size_t)255;
    return p;
  };
  unsigned short* Ps     = (unsigned short*)alloc((size_t)N * 128 * 2);
  unsigned short* Pd     = (unsigned short*)alloc((size_t)N * 128 * 2);
  unsigned short* W1p    = (unsigned short*)alloc(256 * 128 * 2);
  unsigned short* W2b    = (unsigned short*)alloc(128 * 128 * 2);
  unsigned short* N1b    = (unsigned short*)alloc(128 * 256 * 2);
  unsigned short* N2b    = (unsigned short*)alloc(128 * 128 * 2);
  unsigned short* W3b    = (unsigned short*)alloc(128 * 128 * 2);
  float*          w1c    = (float*)alloc(128 * 4);
  int*            deg    = (int*)alloc((size_t)N * 4);
  int*            offs   = (int*)alloc(((size_t)N + 1) * 4);
  int*            cursor = (int*)alloc((size_t)N * 4);
  int*            bsum   = (int*)alloc(256 * 4);
  int2*           sd_s   = (int2*)alloc((size_t)E * 8);
  (void)ws_size;

  int nb = (N + 255) / 256;   // N=50000 -> 196 (<=256 required by scanB; >=128 for prep duty)
  int epairs = (E + 1) / 2;

  hipMemsetAsync(d_out, 0, (size_t)out_size * 4, stream);
  hipMemsetAsync(deg, 0, (size_t)N * 4, stream);

  hist_kernel<<<(epairs + 255) / 256, 256, 0, stream>>>(ei, deg, E);
  scanA_kernel<<<nb, 256, 0, stream>>>(deg, offs, bsum, N,
                                       We1, We2, Wn1, Wn2, Wc1,
                                       W1p, W2b, N1b, N2b, W3b, w1c);
  scanB_kernel<<<1, 256, 0, stream>>>(bsum, offs, nb, N);
  scanC_kernel<<<nb, 256, 0, stream>>>(bsum, offs, cursor, N);
  scatter_kernel<<<(epairs + 255) / 256, 256, 0, stream>>>(ei, cursor, sd_s, E);
  proj_kernel<<<(N + 63) / 64, 256, 0, stream>>>(h, be1, W1p, Ps, Pd, N);
  edge_kernel<<<(E + 63) / 64, 256, 0, stream>>>(Ps, Pd, x, sd_s, w1c,
                                                 be2, bc1, Wc2, W2b, W3b,
                                                 aggH, coordX, E);
  node_kernel<<<(N + 63) / 64, 256, 0, stream>>>(h, x, bn1, bn2, gamma, beta, N1b, N2b,
                                                 aggH, coordX, deg, N);
}